// Round 1
// baseline (313.687 us; speedup 1.0000x reference)
//
#include <hip/hip_runtime.h>

// ---------------- problem constants ----------------
constexpr int B_ = 2, H_ = 512, W_ = 512;
constexpr int HWl = H_ * W_;          // 262144
constexpr int TOT = B_ * HWl;         // 524288
constexpr int KC = 200;               // TOP_K_INSTANCE
constexpr int CAPC = 131072;          // candidate capacity (expected ~21k peaks)
constexpr int NSEG = B_ * (KC + 1);   // 402
constexpr int RADI = 25;              // 3*SIGMA+1
constexpr float INV2S2 = 0.0078125f;  // 1/128, exact power of 2

// output layout (flat float32, concatenated in return order)
constexpr int OUT_CENTER = 0;                 // [B,1,H,W]
constexpr int OUT_OFF = TOT;                  // [B,2,H,W]
constexpr int OUT_CW = TOT + 2 * TOT;         // [B,H,W] ones
constexpr int OUT_OW = OUT_CW + TOT;          // [B,H,W] fg

// ---------------- kernels ----------------

__global__ void k_init(int* cand_count) {
  if (threadIdx.x == 0) *cand_count = 0;
}

// threshold + 7x7 max NMS; append composite key for every peak with v > 0.1
__global__ void k_nms(const float* __restrict__ ctr, unsigned long long* __restrict__ keys,
                      int* __restrict__ cand_count) {
  int i = blockIdx.x * blockDim.x + threadIdx.x;
  if (i >= TOT) return;
  int b = i >> 18, rem = i & (HWl - 1), y = rem >> 9, x = rem & (W_ - 1);
  const float* img = ctr + b * HWl;
  float v = img[rem];
  if (!(v > 0.1f)) return;  // thresholded to -1 -> can never be a valid candidate
  float m = -1.0f;
  int y0 = y - 3; if (y0 < 0) y0 = 0;
  int y1 = y + 3; if (y1 > H_ - 1) y1 = H_ - 1;
  int x0 = x - 3; if (x0 < 0) x0 = 0;
  int x1 = x + 3; if (x1 > W_ - 1) x1 = W_ - 1;
  for (int yy = y0; yy <= y1; ++yy) {
    const float* row = img + yy * W_;
    for (int xx = x0; xx <= x1; ++xx) {
      float w = row[xx];
      float hw = w > 0.1f ? w : -1.0f;
      m = fmaxf(m, hw);
    }
  }
  if (v == m) {  // exact float equality, same as reference hmp==pooled
    unsigned int key32 = __float_as_uint(v);  // v>0 -> bits are order-preserving
    unsigned long long comp = ((unsigned long long)key32 << 32)
                            | (unsigned long long)(0xFFFFFFFFu - (unsigned int)i);
    int slot = atomicAdd(cand_count, 1);
    if (slot < CAPC) keys[slot] = comp;
  }
}

// exact top-K by (value desc, index asc): 64-bit radix select + bitonic rank sort
__global__ __launch_bounds__(1024) void k_topk(
    const unsigned long long* __restrict__ keys, const int* __restrict__ pcnt,
    float* __restrict__ cand_val, int* __restrict__ cand_bid,
    int* __restrict__ cand_cy, int* __restrict__ cand_cx) {
  __shared__ int hist[256];
  __shared__ unsigned long long s_pref;
  __shared__ int s_r;
  __shared__ int s_num;
  __shared__ unsigned long long wins[256];
  int tid = threadIdx.x;
  int M = *pcnt; if (M > CAPC) M = CAPC;

  unsigned long long T = 1ULL;  // if M<=K take everything (all keys > 0)
  if (M > KC) {
    unsigned long long prefix = 0ULL;
    int r = KC;  // looking for the r-th largest (1-indexed)
    for (int pass = 0; pass < 8; ++pass) {
      int shift = 56 - 8 * pass;
      unsigned long long maskhi = (pass == 0) ? 0ULL : (~0ULL << (shift + 8));
      if (tid < 256) hist[tid] = 0;
      __syncthreads();
      for (int idx = tid; idx < M; idx += 1024) {
        unsigned long long kk = keys[idx];
        if ((kk & maskhi) == prefix)
          atomicAdd(&hist[(int)((kk >> shift) & 255ULL)], 1);
      }
      __syncthreads();
      if (tid == 0) {
        int cum = 0;
        for (int bn = 255; bn >= 0; --bn) {
          int h = hist[bn];
          if (cum + h >= r) { prefix |= ((unsigned long long)bn) << shift; r -= cum; break; }
          cum += h;
        }
        s_pref = prefix; s_r = r;
      }
      __syncthreads();
      prefix = s_pref; r = s_r;
      __syncthreads();
    }
    T = prefix;  // exact composite key of rank-K (keys unique -> exactly K winners >= T)
  }

  if (tid == 0) s_num = 0;
  __syncthreads();
  for (int idx = tid; idx < M; idx += 1024) {
    unsigned long long kk = keys[idx];
    if (kk >= T) { int w = atomicAdd(&s_num, 1); if (w < 256) wins[w] = kk; }
  }
  __syncthreads();
  int n = s_num; if (n > 256) n = 256;
  for (int idx = tid; idx < 256; idx += 1024)
    if (idx >= n) wins[idx] = 0ULL;
  __syncthreads();
  // bitonic sort 256 descending
  for (int k2 = 2; k2 <= 256; k2 <<= 1) {
    for (int j = k2 >> 1; j > 0; j >>= 1) {
      if (tid < 256) {
        int l = tid ^ j;
        if (l > tid) {
          unsigned long long a = wins[tid], bq = wins[l];
          bool descseg = ((tid & k2) == 0);
          bool sw = descseg ? (a < bq) : (a > bq);
          if (sw) { wins[tid] = bq; wins[l] = a; }
        }
      }
      __syncthreads();
    }
  }
  if (tid < KC) {
    unsigned long long kk = wins[tid];
    if (kk != 0ULL) {
      unsigned int key32 = (unsigned int)(kk >> 32);
      unsigned int idx = 0xFFFFFFFFu - (unsigned int)(kk & 0xFFFFFFFFULL);
      int b = (int)(idx >> 18), rem = (int)(idx & (HWl - 1));
      cand_val[tid] = __uint_as_float(key32);
      cand_bid[tid] = b; cand_cy[tid] = rem >> 9; cand_cx[tid] = rem & (W_ - 1);
    } else {
      cand_val[tid] = -1e30f; cand_bid[tid] = 0; cand_cy[tid] = 0; cand_cx[tid] = 0;
    }
  }
}

// per-candidate window count of thing pixels (exact integer, == f32 integral image)
__global__ void k_wsum(const int* __restrict__ sem, const float* __restrict__ mix,
                       const float* __restrict__ cand_val, const int* __restrict__ cand_bid,
                       const int* __restrict__ cand_cy, const int* __restrict__ cand_cx,
                       int* __restrict__ selected) {
  __shared__ int ssum[256];
  int k = blockIdx.x;
  int b = cand_bid[k], cy = cand_cy[k], cx = cand_cx[k];
  float v = cand_val[k];
  int y0 = cy - RADI; if (y0 < 0) y0 = 0;
  int y1 = cy + RADI + 1; if (y1 > H_) y1 = H_;
  int x0 = cx - RADI; if (x0 < 0) x0 = 0;
  int x1 = cx + RADI + 1; if (x1 > W_) x1 = W_;
  int wd = x1 - x0, tot = (y1 - y0) * wd;
  int s = 0;
  for (int t = threadIdx.x; t < tot; t += blockDim.x) {
    int yy = y0 + t / wd, xx = x0 + t % wd;
    int sv = sem[b * HWl + yy * W_ + xx];
    s += (sv >= 11 && sv <= 18) ? 1 : 0;
  }
  ssum[threadIdx.x] = s;
  __syncthreads();
  for (int o = 128; o > 0; o >>= 1) {
    if (threadIdx.x < o) ssum[threadIdx.x] += ssum[threadIdx.x + o];
    __syncthreads();
  }
  if (threadIdx.x == 0) {
    bool sel = (v >= 0.1f) && (mix[b * HWl + cy * W_ + cx] < 0.5f) && (ssum[0] >= 64);
    selected[k] = sel ? 1 : 0;
  }
}

// local indices, any_center, compacted selected list (rank order), zero segment sums
__global__ void k_final(const int* __restrict__ cand_bid, const int* __restrict__ cand_cy,
                        const int* __restrict__ cand_cx, const int* __restrict__ selected,
                        int* __restrict__ any_center, int* __restrict__ Sp,
                        int* __restrict__ sel_bid, int* __restrict__ sel_cy,
                        int* __restrict__ sel_cx, int* __restrict__ sel_seg,
                        float* __restrict__ sel_cc,
                        float* __restrict__ sumy, float* __restrict__ sumx,
                        float* __restrict__ cntf) {
  __shared__ int slocal[KC];
  int k = threadIdx.x;
  for (int t = k; t < NSEG; t += blockDim.x) { sumy[t] = 0.f; sumx[t] = 0.f; cntf[t] = 0.f; }
  if (k < B_) any_center[k] = 0;
  if (k < KC) {
    int b = cand_bid[k], c = 0;
    for (int j = 0; j < k; ++j) c += (selected[j] && cand_bid[j] == b) ? 1 : 0;
    slocal[k] = c + 1;  // local index + 1 (seg id if chosen)
  }
  __syncthreads();
  if (k == 0) {
    int S = 0;
    for (int j = 0; j < KC; ++j) {
      if (selected[j]) {
        int b = cand_bid[j];
        sel_bid[S] = b; sel_cy[S] = cand_cy[j]; sel_cx[S] = cand_cx[j];
        sel_seg[S] = slocal[j];
        float cy = (float)cand_cy[j], cx = (float)cand_cx[j];
        sel_cc[S] = __fadd_rn(__fmul_rn(cy, cy), __fmul_rn(cx, cx));
        any_center[b] = 1;
        ++S;
      }
    }
    *Sp = S;
  }
}

// Gaussian max-splat into center heatmap
__global__ void k_center(const int* __restrict__ Sp, const int* __restrict__ sel_bid,
                         const int* __restrict__ sel_cy, const int* __restrict__ sel_cx,
                         float* __restrict__ out) {
  __shared__ int sb[KC], sy[KC], sx[KC];
  __shared__ int Ss;
  if (threadIdx.x == 0) Ss = *Sp;
  __syncthreads();
  int S = Ss;
  for (int t = threadIdx.x; t < S; t += blockDim.x) {
    sb[t] = sel_bid[t]; sy[t] = sel_cy[t]; sx[t] = sel_cx[t];
  }
  __syncthreads();
  int i = blockIdx.x * blockDim.x + threadIdx.x;
  int b = i >> 18, rem = i & (HWl - 1), y = rem >> 9, x = rem & (W_ - 1);
  float best = 0.0f;  // segment_max then max(.,0): 0 baseline
  for (int s = 0; s < S; ++s) {
    if (sb[s] != b) continue;
    int dy = y - sy[s]; if (dy < -RADI || dy > RADI) continue;
    int dx = x - sx[s]; if (dx < -RADI || dx > RADI) continue;
    float gy = expf(-(float)(dy * dy) * INV2S2);  // exact input: d2<=625 * 2^-7
    float gx = expf(-(float)(dx * dx) * INV2S2);
    best = fmaxf(best, __fmul_rn(gy, gx));
  }
  out[OUT_CENTER + i] = best;
}

// nearest-center argmin (exact replication of expanded-quadratic f32 ops),
// instance ids, weights, segment mass sums via wave-segmented atomics
__global__ void k_group(const float* __restrict__ offs, const int* __restrict__ sem,
                        const int* __restrict__ Sp, const int* __restrict__ sel_bid,
                        const int* __restrict__ sel_cy, const int* __restrict__ sel_cx,
                        const int* __restrict__ sel_seg, const float* __restrict__ sel_cc,
                        const int* __restrict__ any_center,
                        int* __restrict__ ins, float* __restrict__ out,
                        float* __restrict__ sumy, float* __restrict__ sumx,
                        float* __restrict__ cntf) {
  __shared__ int sb[KC], sseg[KC];
  __shared__ float scy[KC], scx[KC], scc[KC];
  __shared__ int Ss;
  if (threadIdx.x == 0) Ss = *Sp;
  __syncthreads();
  int S = Ss;
  for (int t = threadIdx.x; t < S; t += blockDim.x) {
    sb[t] = sel_bid[t]; sseg[t] = sel_seg[t];
    scy[t] = (float)sel_cy[t]; scx[t] = (float)sel_cx[t]; scc[t] = sel_cc[t];
  }
  __syncthreads();
  int i = blockIdx.x * blockDim.x + threadIdx.x;
  int b = i >> 18, rem = i & (HWl - 1), y = rem >> 9, x = rem & (W_ - 1);
  float offy = offs[b * (2 * HWl) + rem];
  float offx = offs[b * (2 * HWl) + HWl + rem];
  // exact op order of reference: ll = ly*ly + lx*lx ; d2 = (cc - 2*dot) + ll ; no FMA
  float ly = __fadd_rn((float)y, offy);
  float lx = __fadd_rn((float)x, offx);
  float ll = __fadd_rn(__fmul_rn(ly, ly), __fmul_rn(lx, lx));
  float bestd = 3.0e38f;
  int bestseg = 0;
  for (int s = 0; s < S; ++s) {   // ascending rank k -> argmin first-min tie-break
    if (sb[s] != b) continue;
    float dot = __fadd_rn(__fmul_rn(scy[s], ly), __fmul_rn(scx[s], lx));
    float d2 = __fadd_rn(__fsub_rn(scc[s], __fmul_rn(2.0f, dot)), ll);
    if (d2 < bestd) { bestd = d2; bestseg = sseg[s]; }
  }
  int sv = sem[i];
  bool thing = (sv >= 11 && sv <= 18);
  int insv = (thing && any_center[b]) ? bestseg : 0;
  ins[i] = insv;
  bool fg = insv > 0;
  out[OUT_CW + i] = 1.0f;
  out[OUT_OW + i] = fg ? 1.0f : 0.0f;

  // wave-segmented accumulation: few atomics per wave, low contention
  int seg = b * (KC + 1) + insv;
  int lane = threadIdx.x & 63;
  unsigned long long remm = __ballot(fg);
  while (remm) {
    int leader = __ffsll((unsigned long long)remm) - 1;
    int segl = __shfl(seg, leader);
    bool mine = fg && (seg == segl);
    unsigned long long grp = __ballot(mine);
    float ys = mine ? (float)y : 0.0f;
    float xs = mine ? (float)x : 0.0f;
    float cs = mine ? 1.0f : 0.0f;
#pragma unroll
    for (int o = 32; o > 0; o >>= 1) {
      ys += __shfl_xor(ys, o);
      xs += __shfl_xor(xs, o);
      cs += __shfl_xor(cs, o);
    }
    if (lane == leader) {
      atomicAdd(&sumy[segl], ys);
      atomicAdd(&sumx[segl], xs);
      atomicAdd(&cntf[segl], cs);
    }
    remm &= ~grp;
  }
}

// offset pseudo labels: mass-center minus pixel coord
__global__ void k_off(const int* __restrict__ ins, const float* __restrict__ sumy,
                      const float* __restrict__ sumx, const float* __restrict__ cntf,
                      float* __restrict__ out) {
  int i = blockIdx.x * blockDim.x + threadIdx.x;
  int b = i >> 18, rem = i & (HWl - 1), y = rem >> 9, x = rem & (W_ - 1);
  int insv = ins[i];
  float oy = 0.0f, ox = 0.0f;
  if (insv > 0) {
    int sg = b * (KC + 1) + insv;
    float c = fmaxf(cntf[sg], 1.0f);
    oy = __fsub_rn(sumy[sg] / c, (float)y);
    ox = __fsub_rn(sumx[sg] / c, (float)x);
  }
  out[OUT_OFF + b * (2 * HWl) + rem] = oy;
  out[OUT_OFF + b * (2 * HWl) + HWl + rem] = ox;
}

// ---------------- launch ----------------
extern "C" void kernel_launch(void* const* d_in, const int* in_sizes, int n_in,
                              void* d_out, int out_size, void* d_ws, size_t ws_size,
                              hipStream_t stream) {
  const float* ctr = (const float*)d_in[0];
  const float* offs = (const float*)d_in[1];
  const int* sem = (const int*)d_in[2];
  const float* mix = (const float*)d_in[3];
  float* out = (float*)d_out;

  char* w = (char*)d_ws;
  unsigned long long* keys = (unsigned long long*)w;   // 1 MB
  char* p = w + (size_t)CAPC * 8;
  int* cand_count = (int*)(p + 0);
  int* Sp = (int*)(p + 4);
  int* any_center = (int*)(p + 16);
  float* cand_val = (float*)(p + 1024);
  int* cand_bid = (int*)(p + 2048);
  int* cand_cy = (int*)(p + 3072);
  int* cand_cx = (int*)(p + 4096);
  int* selected = (int*)(p + 5120);
  int* sel_bid = (int*)(p + 7168);
  int* sel_cy = (int*)(p + 8192);
  int* sel_cx = (int*)(p + 9216);
  int* sel_seg = (int*)(p + 10240);
  float* sel_cc = (float*)(p + 11264);
  float* sumy = (float*)(p + 12288);
  float* sumx = (float*)(p + 14336);
  float* cntf = (float*)(p + 16384);
  int* ins = (int*)(p + 20480);                        // 2 MB

  k_init<<<1, 64, 0, stream>>>(cand_count);
  k_nms<<<TOT / 256, 256, 0, stream>>>(ctr, keys, cand_count);
  k_topk<<<1, 1024, 0, stream>>>(keys, cand_count, cand_val, cand_bid, cand_cy, cand_cx);
  k_wsum<<<KC, 256, 0, stream>>>(sem, mix, cand_val, cand_bid, cand_cy, cand_cx, selected);
  k_final<<<1, 256, 0, stream>>>(cand_bid, cand_cy, cand_cx, selected, any_center, Sp,
                                 sel_bid, sel_cy, sel_cx, sel_seg, sel_cc, sumy, sumx, cntf);
  k_center<<<TOT / 256, 256, 0, stream>>>(Sp, sel_bid, sel_cy, sel_cx, out);
  k_group<<<TOT / 256, 256, 0, stream>>>(offs, sem, Sp, sel_bid, sel_cy, sel_cx, sel_seg,
                                         sel_cc, any_center, ins, out, sumy, sumx, cntf);
  k_off<<<TOT / 256, 256, 0, stream>>>(ins, sumy, sumx, cntf, out);
}

// Round 2
// 214.826 us; speedup vs baseline: 1.4602x; 1.4602x over previous
//
#include <hip/hip_runtime.h>

// ---------------- problem constants ----------------
constexpr int B_ = 2, H_ = 512, W_ = 512;
constexpr int HWl = H_ * W_;          // 262144
constexpr int TOT = B_ * HWl;         // 524288
constexpr int KC = 200;               // TOP_K_INSTANCE
constexpr int CAPC = 131072;          // candidate capacity
constexpr int NSEG = B_ * (KC + 1);   // 402
constexpr int RADI = 25;              // 3*SIGMA+1
constexpr float INV2S2 = 0.0078125f;  // 1/128, exact power of 2

// output layout (flat float32, concatenated in return order)
constexpr int OUT_CENTER = 0;                 // [B,1,H,W]
constexpr int OUT_OFF = TOT;                  // [B,2,H,W]
constexpr int OUT_CW = TOT + 2 * TOT;         // [B,H,W] ones
constexpr int OUT_OW = OUT_CW + TOT;          // [B,H,W] fg

// ---------------- kernels ----------------

__global__ void k_init(int* cand_count) {
  if (threadIdx.x == 0) *cand_count = 0;
}

// threshold + 7x7 max NMS; append composite key for every peak with v > 0.1
__global__ void k_nms(const float* __restrict__ ctr, unsigned long long* __restrict__ keys,
                      int* __restrict__ cand_count) {
  int i = blockIdx.x * blockDim.x + threadIdx.x;
  if (i >= TOT) return;
  int b = i >> 18, rem = i & (HWl - 1), y = rem >> 9, x = rem & (W_ - 1);
  const float* img = ctr + b * HWl;
  float v = img[rem];
  if (!(v > 0.1f)) return;  // thresholded to -1 -> can never be a valid candidate
  float m = -1.0f;
  int y0 = y - 3; if (y0 < 0) y0 = 0;
  int y1 = y + 3; if (y1 > H_ - 1) y1 = H_ - 1;
  int x0 = x - 3; if (x0 < 0) x0 = 0;
  int x1 = x + 3; if (x1 > W_ - 1) x1 = W_ - 1;
  for (int yy = y0; yy <= y1; ++yy) {
    const float* row = img + yy * W_;
    for (int xx = x0; xx <= x1; ++xx) {
      float w = row[xx];
      float hw = w > 0.1f ? w : -1.0f;
      m = fmaxf(m, hw);
    }
  }
  if (v == m) {  // exact float equality, same as reference hmp==pooled
    unsigned int key32 = __float_as_uint(v);  // v>0 -> bits order-preserving
    unsigned long long comp = ((unsigned long long)key32 << 32)
                            | (unsigned long long)(0xFFFFFFFFu - (unsigned int)i);
    int slot = atomicAdd(cand_count, 1);
    if (slot < CAPC) keys[slot] = comp;
  }
}

// exact top-K by (value desc, index asc): 64-bit radix select (parallel bin scan)
// + bitonic rank sort of the <=256 winners
__global__ __launch_bounds__(1024) void k_topk(
    const unsigned long long* __restrict__ keys, const int* __restrict__ pcnt,
    float* __restrict__ cand_val, int* __restrict__ cand_bid,
    int* __restrict__ cand_cy, int* __restrict__ cand_cx) {
  __shared__ int hist[256];
  __shared__ int sfx[256];
  __shared__ unsigned long long s_pref;
  __shared__ int s_r;
  __shared__ int s_num;
  __shared__ unsigned long long wins[256];
  int tid = threadIdx.x;
  int M = *pcnt; if (M > CAPC) M = CAPC;

  unsigned long long T = 1ULL;  // if M<=K take everything (all keys nonzero)
  if (M > KC) {
    unsigned long long prefix = 0ULL;
    int r = KC;  // r-th largest (1-indexed)
    for (int pass = 0; pass < 8; ++pass) {
      int shift = 56 - 8 * pass;
      unsigned long long maskhi = (pass == 0) ? 0ULL : (~0ULL << (shift + 8));
      if (tid < 256) hist[tid] = 0;
      __syncthreads();
      for (int idx = tid; idx < M; idx += 1024) {
        unsigned long long kk = keys[idx];
        if ((kk & maskhi) == prefix)
          atomicAdd(&hist[(int)((kk >> shift) & 255ULL)], 1);
      }
      __syncthreads();
      if (tid < 256) sfx[tid] = hist[tid];
      __syncthreads();
      // suffix sums: sfx[b] = sum_{j>=b} hist[j]
      for (int off = 1; off < 256; off <<= 1) {
        int v = 0;
        if (tid < 256 && tid + off < 256) v = sfx[tid + off];
        __syncthreads();
        if (tid < 256) sfx[tid] += v;
        __syncthreads();
      }
      // the target bin: largest bn with sfx[bn] >= r  (sfx non-increasing in bn)
      if (tid < 256) {
        bool cond = sfx[tid] >= r;
        bool last = (tid == 255) || (sfx[tid + 1] < r);
        if (cond && last) {
          s_pref = prefix | ((unsigned long long)tid << shift);
          s_r = r - ((tid < 255) ? sfx[tid + 1] : 0);
        }
      }
      __syncthreads();
      prefix = s_pref; r = s_r;
      __syncthreads();
    }
    T = prefix;  // exact composite key of rank-K (keys unique -> exactly K >= T)
  }

  if (tid == 0) s_num = 0;
  __syncthreads();
  for (int idx = tid; idx < M; idx += 1024) {
    unsigned long long kk = keys[idx];
    if (kk >= T) { int w = atomicAdd(&s_num, 1); if (w < 256) wins[w] = kk; }
  }
  __syncthreads();
  int n = s_num; if (n > 256) n = 256;
  if (tid < 256 && tid >= n) wins[tid] = 0ULL;
  __syncthreads();
  // bitonic sort 256 descending
  for (int k2 = 2; k2 <= 256; k2 <<= 1) {
    for (int j = k2 >> 1; j > 0; j >>= 1) {
      if (tid < 256) {
        int l = tid ^ j;
        if (l > tid) {
          unsigned long long a = wins[tid], bq = wins[l];
          bool descseg = ((tid & k2) == 0);
          bool sw = descseg ? (a < bq) : (a > bq);
          if (sw) { wins[tid] = bq; wins[l] = a; }
        }
      }
      __syncthreads();
    }
  }
  if (tid < KC) {
    unsigned long long kk = wins[tid];
    if (kk != 0ULL) {
      unsigned int key32 = (unsigned int)(kk >> 32);
      unsigned int idx = 0xFFFFFFFFu - (unsigned int)(kk & 0xFFFFFFFFULL);
      int b = (int)(idx >> 18), rem = (int)(idx & (HWl - 1));
      cand_val[tid] = __uint_as_float(key32);
      cand_bid[tid] = b; cand_cy[tid] = rem >> 9; cand_cx[tid] = rem & (W_ - 1);
    } else {
      cand_val[tid] = -1e30f; cand_bid[tid] = 0; cand_cy[tid] = 0; cand_cx[tid] = 0;
    }
  }
}

// per-candidate window count of thing pixels (exact integer == f32 integral image)
__global__ void k_wsum(const int* __restrict__ sem, const float* __restrict__ mix,
                       const float* __restrict__ cand_val, const int* __restrict__ cand_bid,
                       const int* __restrict__ cand_cy, const int* __restrict__ cand_cx,
                       int* __restrict__ selected) {
  __shared__ int ssum[256];
  int k = blockIdx.x;
  int b = cand_bid[k], cy = cand_cy[k], cx = cand_cx[k];
  float v = cand_val[k];
  int y0 = cy - RADI; if (y0 < 0) y0 = 0;
  int y1 = cy + RADI + 1; if (y1 > H_) y1 = H_;
  int x0 = cx - RADI; if (x0 < 0) x0 = 0;
  int x1 = cx + RADI + 1; if (x1 > W_) x1 = W_;
  int wd = x1 - x0, tot = (y1 - y0) * wd;
  int s = 0;
  for (int t = threadIdx.x; t < tot; t += blockDim.x) {
    int yy = y0 + t / wd, xx = x0 + t % wd;
    int sv = sem[b * HWl + yy * W_ + xx];
    s += (sv >= 11 && sv <= 18) ? 1 : 0;
  }
  ssum[threadIdx.x] = s;
  __syncthreads();
  for (int o = 128; o > 0; o >>= 1) {
    if (threadIdx.x < o) ssum[threadIdx.x] += ssum[threadIdx.x + o];
    __syncthreads();
  }
  if (threadIdx.x == 0) {
    bool sel = (v >= 0.1f) && (mix[b * HWl + cy * W_ + cx] < 0.5f) && (ssum[0] >= 64);
    selected[k] = sel ? 1 : 0;
  }
}

// fully parallel: build per-batch packed center lists (rank order preserved),
// any_center, per-batch counts; zero segment sums
__global__ __launch_bounds__(256) void k_final(
    const int* __restrict__ cand_bid, const int* __restrict__ cand_cy,
    const int* __restrict__ cand_cx, const int* __restrict__ selected,
    int* __restrict__ any_center, int* __restrict__ Sb,
    float4* __restrict__ sel_pack,
    int* __restrict__ sumy, int* __restrict__ sumx, int* __restrict__ cnti) {
  __shared__ int wtot0[4], wtot1[4];
  int k = threadIdx.x;
  for (int t = k; t < NSEG; t += 256) { sumy[t] = 0; sumx[t] = 0; cnti[t] = 0; }
  if (k < B_) any_center[k] = 0;
  bool sel = false; int b = 0, cy = 0, cx = 0;
  if (k < KC) { sel = selected[k] != 0; b = cand_bid[k]; cy = cand_cy[k]; cx = cand_cx[k]; }
  unsigned long long m0 = __ballot(sel && b == 0);
  unsigned long long m1 = __ballot(sel && b == 1);
  int lane = k & 63, wv = k >> 6;
  if (lane == 0) { wtot0[wv] = __popcll(m0); wtot1[wv] = __popcll(m1); }
  __syncthreads();
  int base0 = 0, base1 = 0;
  for (int w2 = 0; w2 < wv; ++w2) { base0 += wtot0[w2]; base1 += wtot1[w2]; }
  unsigned long long below = (1ULL << lane) - 1ULL;
  int p0 = base0 + __popcll(m0 & below);
  int p1 = base1 + __popcll(m1 & below);
  if (sel) {
    int lidx = (b == 0) ? p0 : p1;  // 0-based local index (ascending rank k)
    float fy = (float)cy, fx = (float)cx;
    float cc = __fadd_rn(__fmul_rn(fy, fy), __fmul_rn(fx, fx));
    sel_pack[b * 256 + lidx] = make_float4(fy, fx, cc, 0.0f);
    if (lidx == 0) any_center[b] = 1;
  }
  if (k == 0) {
    int t0 = 0, t1 = 0;
    for (int w2 = 0; w2 < 4; ++w2) { t0 += wtot0[w2]; t1 += wtot1[w2]; }
    Sb[0] = t0; Sb[1] = t1;
  }
}

// fused: Gaussian max-splat + nearest-center argmin + weights + integer mass sums
__global__ __launch_bounds__(256) void k_fused(
    const float* __restrict__ offs, const int* __restrict__ sem,
    const int* __restrict__ Sb, const float4* __restrict__ sel_pack,
    const int* __restrict__ any_center,
    int* __restrict__ ins, float* __restrict__ out,
    int* __restrict__ sumy, int* __restrict__ sumx, int* __restrict__ cnti) {
  __shared__ float4 sc[256];
  __shared__ int Ss, s_any;
  int i = blockIdx.x * 256 + threadIdx.x;
  int b = i >> 18;  // uniform per block (HWl % 256 == 0)
  if (threadIdx.x == 0) { Ss = Sb[b]; s_any = any_center[b]; }
  __syncthreads();
  int S = Ss;
  for (int t = threadIdx.x; t < S; t += 256) sc[t] = sel_pack[b * 256 + t];
  __syncthreads();
  int rem = i & (HWl - 1), y = rem >> 9, x = rem & (W_ - 1);
  float offy = offs[b * (2 * HWl) + rem];
  float offx = offs[b * (2 * HWl) + HWl + rem];
  float fy = (float)y, fx = (float)x;
  // exact op order of reference: ll = ly*ly + lx*lx ; d2 = (cc - 2*dot) + ll ; no FMA
  float ly = __fadd_rn(fy, offy), lx = __fadd_rn(fx, offx);
  float ll = __fadd_rn(__fmul_rn(ly, ly), __fmul_rn(lx, lx));
  float bestd = 3.0e38f, bestg = 0.0f;
  int bestseg = 0;
  for (int s = 0; s < S; ++s) {
    float4 c = sc[s];
    float dot = __fadd_rn(__fmul_rn(c.x, ly), __fmul_rn(c.y, lx));
    float d2 = __fadd_rn(__fsub_rn(c.z, __fmul_rn(2.0f, dot)), ll);
    bool better = d2 < bestd;  // ascending rank -> first-min tie-break (== argmin)
    bestd = better ? d2 : bestd;
    bestseg = better ? (s + 1) : bestseg;
    float dy = fy - c.x, dx = fx - c.y;
    if (fabsf(dy) <= 25.0f && fabsf(dx) <= 25.0f) {
      float gy = expf(-__fmul_rn(__fmul_rn(dy, dy), INV2S2));
      float gx = expf(-__fmul_rn(__fmul_rn(dx, dx), INV2S2));
      bestg = fmaxf(bestg, __fmul_rn(gy, gx));
    }
  }
  out[OUT_CENTER + i] = bestg;
  int sv = sem[i];
  bool thing = (sv >= 11 && sv <= 18);
  int insv = (thing && s_any) ? bestseg : 0;
  ins[i] = insv;
  bool fg = insv > 0;
  out[OUT_CW + i] = 1.0f;
  out[OUT_OW + i] = fg ? 1.0f : 0.0f;

  // wave-segmented integer accumulation (few atomics per wave, exact & deterministic)
  int seg = b * (KC + 1) + insv;
  int lane = threadIdx.x & 63;
  unsigned long long remm = __ballot(fg);
  while (remm) {
    int leader = __ffsll((unsigned long long)remm) - 1;
    int segl = __shfl(seg, leader);
    bool mine = fg && (seg == segl);
    unsigned long long grp = __ballot(mine);
    int ysv = mine ? y : 0, xsv = mine ? x : 0, csv = mine ? 1 : 0;
#pragma unroll
    for (int o = 32; o > 0; o >>= 1) {
      ysv += __shfl_xor(ysv, o);
      xsv += __shfl_xor(xsv, o);
      csv += __shfl_xor(csv, o);
    }
    if (lane == leader) {
      atomicAdd(&sumy[segl], ysv);
      atomicAdd(&sumx[segl], xsv);
      atomicAdd(&cnti[segl], csv);
    }
    remm &= ~grp;
  }
}

// offset pseudo labels: mass-center minus pixel coord
__global__ void k_off(const int* __restrict__ ins, const int* __restrict__ sumy,
                      const int* __restrict__ sumx, const int* __restrict__ cnti,
                      float* __restrict__ out) {
  int i = blockIdx.x * blockDim.x + threadIdx.x;
  int b = i >> 18, rem = i & (HWl - 1), y = rem >> 9, x = rem & (W_ - 1);
  int insv = ins[i];
  float oy = 0.0f, ox = 0.0f;
  if (insv > 0) {
    int sg = b * (KC + 1) + insv;
    float c = fmaxf((float)cnti[sg], 1.0f);
    oy = __fsub_rn((float)sumy[sg] / c, (float)y);
    ox = __fsub_rn((float)sumx[sg] / c, (float)x);
  }
  out[OUT_OFF + b * (2 * HWl) + rem] = oy;
  out[OUT_OFF + b * (2 * HWl) + HWl + rem] = ox;
}

// ---------------- launch ----------------
extern "C" void kernel_launch(void* const* d_in, const int* in_sizes, int n_in,
                              void* d_out, int out_size, void* d_ws, size_t ws_size,
                              hipStream_t stream) {
  const float* ctr = (const float*)d_in[0];
  const float* offs = (const float*)d_in[1];
  const int* sem = (const int*)d_in[2];
  const float* mix = (const float*)d_in[3];
  float* out = (float*)d_out;

  char* w = (char*)d_ws;
  unsigned long long* keys = (unsigned long long*)w;   // 1 MB
  char* p = w + (size_t)CAPC * 8;
  int* cand_count = (int*)(p + 0);
  int* any_center = (int*)(p + 16);
  int* Sb = (int*)(p + 32);
  float* cand_val = (float*)(p + 1024);
  int* cand_bid = (int*)(p + 2048);
  int* cand_cy = (int*)(p + 3072);
  int* cand_cx = (int*)(p + 4096);
  int* selected = (int*)(p + 5120);
  int* sumy = (int*)(p + 6144);
  int* sumx = (int*)(p + 8192);
  int* cnti = (int*)(p + 10240);
  float4* sel_pack = (float4*)(p + 16384);             // 2*256*16 = 8 KB
  int* ins = (int*)(p + 32768);                        // 2 MB

  k_init<<<1, 64, 0, stream>>>(cand_count);
  k_nms<<<TOT / 256, 256, 0, stream>>>(ctr, keys, cand_count);
  k_topk<<<1, 1024, 0, stream>>>(keys, cand_count, cand_val, cand_bid, cand_cy, cand_cx);
  k_wsum<<<KC, 256, 0, stream>>>(sem, mix, cand_val, cand_bid, cand_cy, cand_cx, selected);
  k_final<<<1, 256, 0, stream>>>(cand_bid, cand_cy, cand_cx, selected, any_center, Sb,
                                 sel_pack, sumy, sumx, cnti);
  k_fused<<<TOT / 256, 256, 0, stream>>>(offs, sem, Sb, sel_pack, any_center,
                                         ins, out, sumy, sumx, cnti);
  k_off<<<TOT / 256, 256, 0, stream>>>(ins, sumy, sumx, cnti, out);
}

// Round 4
// 151.829 us; speedup vs baseline: 2.0661x; 1.4149x over previous
//
#include <hip/hip_runtime.h>

// ---------------- problem constants ----------------
constexpr int B_ = 2, H_ = 512, W_ = 512;
constexpr int HWl = H_ * W_;          // 262144
constexpr int TOT = B_ * HWl;         // 524288
constexpr int KC = 200;               // TOP_K_INSTANCE
constexpr int CAPC = 65536;           // candidate capacity (expect ~11k peaks)
constexpr int NSEG = B_ * (KC + 1);   // 402
constexpr float INV2S2 = 0.0078125f;  // 1/128, exact power of 2

// output layout (flat float32, concatenated in return order)
constexpr int OUT_CENTER = 0;                 // [B,1,H,W]
constexpr int OUT_OFF = TOT;                  // [B,2,H,W]
constexpr int OUT_CW = TOT + 2 * TOT;         // [B,H,W] ones
constexpr int OUT_OW = OUT_CW + TOT;          // [B,H,W] fg

constexpr int ZERO_INT4 = 17056;              // 272896 B zero region (hist+meta+sums)

__device__ __forceinline__ float hwthr(float v) { return v > 0.1f ? v : -1.0f; }

// ---------------- kernels ----------------

// pass 1: horizontal 7-max of thresholded heatmap (4 px/thread).
// First blocks also zero the ws meta region (hist16 + counters + segment sums).
__global__ __launch_bounds__(256) void k_rowmax(const float* __restrict__ ctr,
                                                float* __restrict__ rowmax,
                                                int4* __restrict__ zbuf) {
  int t = blockIdx.x * 256 + threadIdx.x;     // t < 131072
  if (t < ZERO_INT4) zbuf[t] = make_int4(0, 0, 0, 0);
  int p = t << 2;
  int x4 = p & (W_ - 1);
  const float4* c4 = (const float4*)ctr;
  float4 v = c4[t];
  float4 L = make_float4(-1e30f, -1e30f, -1e30f, -1e30f), R = L;
  if (x4 >= 4) L = c4[t - 1];
  if (x4 <= W_ - 8) R = c4[t + 1];
  float a1 = hwthr(L.y), a2 = hwthr(L.z), a3 = hwthr(L.w);
  float a4 = hwthr(v.x), a5 = hwthr(v.y), a6 = hwthr(v.z), a7 = hwthr(v.w);
  float a8 = hwthr(R.x), a9 = hwthr(R.y), a10 = hwthr(R.z);
  float core = fmaxf(fmaxf(a4, a5), fmaxf(a6, a7));
  float4 m;
  m.x = fmaxf(fmaxf(a1, a2), fmaxf(a3, core));
  m.y = fmaxf(fmaxf(a2, a3), fmaxf(core, a8));
  m.z = fmaxf(fmaxf(a3, core), fmaxf(a8, a9));
  m.w = fmaxf(fmaxf(core, a8), fmaxf(a9, a10));
  ((float4*)rowmax)[t] = m;
}

// pass 2: vertical 7-max of rowmax -> pooled; peak emit (key + 16-bit-prefix hist)
__global__ __launch_bounds__(256) void k_nms2(const float* __restrict__ ctr,
                                              const float* __restrict__ rowmax,
                                              unsigned long long* __restrict__ keys,
                                              int* __restrict__ cand_count,
                                              int* __restrict__ hist16) {
  int t = blockIdx.x * 256 + threadIdx.x;     // t < 131072
  int p = t << 2;
  int rem = p & (HWl - 1), y = rem >> 9;
  const float4* rm4 = (const float4*)rowmax;
  float4 pool = make_float4(-1e30f, -1e30f, -1e30f, -1e30f);
#pragma unroll
  for (int dy = -3; dy <= 3; ++dy) {
    int yy = y + dy;
    if (yy < 0 || yy >= H_) continue;
    float4 r = rm4[t + dy * (W_ / 4)];
    pool.x = fmaxf(pool.x, r.x); pool.y = fmaxf(pool.y, r.y);
    pool.z = fmaxf(pool.z, r.z); pool.w = fmaxf(pool.w, r.w);
  }
  float4 v = ((const float4*)ctr)[t];
  float vv[4] = {v.x, v.y, v.z, v.w};
  float pv[4] = {pool.x, pool.y, pool.z, pool.w};
#pragma unroll
  for (int j = 0; j < 4; ++j) {
    float vj = vv[j];
    if (vj > 0.1f && vj == pv[j]) {  // exact equality, same as reference hmp==pooled
      unsigned int i = (unsigned int)(p + j);
      unsigned int key32 = __float_as_uint(vj);  // v>0 -> bits order-preserving
      unsigned long long comp = ((unsigned long long)key32 << 32)
                              | (unsigned long long)(0xFFFFFFFFu - i);
      int slot = atomicAdd(cand_count, 1);
      if (slot < CAPC) keys[slot] = comp;
      atomicAdd(&hist16[key32 >> 16], 1);
    }
  }
}

// exact top-K by (value desc, index asc).
// Level 1: suffix-scan the 64K-bin (value bits [31:16]) histogram -> bin P1 + rank r1.
// Levels 2,3: two LDS-histogram scans refine to the EXACT 32-bit value V of the
// rank-K key. Collect keys with value >= V (<= K-1 + exact-value ties entries),
// bitonic sort 1024 desc, emit rank order.
__global__ __launch_bounds__(1024) void k_topk2(
    const unsigned long long* __restrict__ keys, const int* __restrict__ pcnt,
    const int* __restrict__ hist,
    float* __restrict__ cand_val, int* __restrict__ cand_bid,
    int* __restrict__ cand_cy, int* __restrict__ cand_cx) {
  __shared__ int sfxC[1024];
  __shared__ int hs[256];
  __shared__ int s_tc, s_A, s_bin, s_r, s_num;
  __shared__ unsigned long long wins[1024];
  int tid = threadIdx.x;
  int M = *pcnt; if (M > CAPC) M = CAPC;
  int Kt = M < KC ? M : KC;

  unsigned long long thresh64 = 1ULL;  // M<=K: take everything (all keys nonzero)
  if (M > KC) {
    // ---- level 1: 64K bins via precomputed global hist ----
    const int4* h4 = (const int4*)hist;
    int cs = 0;
#pragma unroll
    for (int it = 0; it < 16; ++it) {
      int4 hv = h4[tid * 16 + it];
      cs += hv.x + hv.y + hv.z + hv.w;
    }
    sfxC[tid] = cs;
    __syncthreads();
    for (int off = 1; off < 1024; off <<= 1) {
      int v = (tid + off < 1024) ? sfxC[tid + off] : 0;
      __syncthreads();
      sfxC[tid] += v;
      __syncthreads();
    }
    if (sfxC[tid] >= Kt && (tid == 1023 || sfxC[tid + 1] < Kt)) {
      s_tc = tid;
      s_A = (tid == 1023) ? 0 : sfxC[tid + 1];
    }
    __syncthreads();
    int tc = s_tc, A = s_A;
    if (tid < 64) hs[tid] = hist[tc * 64 + tid];
    __syncthreads();
    for (int off = 1; off < 64; off <<= 1) {
      int v = 0;
      if (tid < 64 && tid + off < 64) v = hs[tid + off];
      __syncthreads();
      if (tid < 64) hs[tid] += v;
      __syncthreads();
    }
    if (tid < 64) {
      int above = A + ((tid == 63) ? 0 : hs[tid + 1]);
      if (A + hs[tid] >= Kt && above < Kt) { s_bin = tc * 64 + tid; s_r = Kt - above; }
    }
    __syncthreads();
    unsigned int P1 = (unsigned int)s_bin;  // value bits [31:16]
    int r1 = s_r;                           // rank within bin P1 (1-indexed from top)
    __syncthreads();

    // ---- level 2: 256 bins on value bits [15:8] among keys with v[31:16]==P1 ----
    if (tid < 256) hs[tid] = 0;
    __syncthreads();
    for (int idx = tid; idx < M; idx += 1024) {
      unsigned long long kk = keys[idx];
      if ((unsigned int)(kk >> 48) == P1)
        atomicAdd(&hs[(int)((kk >> 40) & 255ULL)], 1);
    }
    __syncthreads();
    for (int off = 1; off < 256; off <<= 1) {
      int v = 0;
      if (tid < 256 && tid + off < 256) v = hs[tid + off];
      __syncthreads();
      if (tid < 256) hs[tid] += v;
      __syncthreads();
    }
    if (tid < 256) {
      int above = (tid == 255) ? 0 : hs[tid + 1];
      if (hs[tid] >= r1 && above < r1) { s_bin = tid; s_r = r1 - above; }
    }
    __syncthreads();
    unsigned int P2 = (P1 << 8) | (unsigned int)s_bin;  // value bits [31:8]
    int r2 = s_r;
    __syncthreads();

    // ---- level 3: 256 bins on value bits [7:0] among keys with v[31:8]==P2 ----
    if (tid < 256) hs[tid] = 0;
    __syncthreads();
    for (int idx = tid; idx < M; idx += 1024) {
      unsigned long long kk = keys[idx];
      if ((unsigned int)(kk >> 40) == P2)
        atomicAdd(&hs[(int)((kk >> 32) & 255ULL)], 1);
    }
    __syncthreads();
    for (int off = 1; off < 256; off <<= 1) {
      int v = 0;
      if (tid < 256 && tid + off < 256) v = hs[tid + off];
      __syncthreads();
      if (tid < 256) hs[tid] += v;
      __syncthreads();
    }
    if (tid < 256) {
      int above = (tid == 255) ? 0 : hs[tid + 1];
      if (hs[tid] >= r2 && above < r2) s_bin = tid;
    }
    __syncthreads();
    unsigned int V = (P2 << 8) | (unsigned int)s_bin;   // exact rank-K 32-bit value
    thresh64 = ((unsigned long long)V) << 32;           // value>=V  <=>  key>=thresh64
  }

  if (tid == 0) s_num = 0;
  __syncthreads();
  for (int idx = tid; idx < M; idx += 1024) {
    unsigned long long kk = keys[idx];
    if (kk >= thresh64) {
      int w = atomicAdd(&s_num, 1);
      if (w < 1024) wins[w] = kk;
    }
  }
  __syncthreads();
  int n = s_num; if (n > 1024) n = 1024;
  if (tid >= n) wins[tid] = 0ULL;
  __syncthreads();
  // bitonic sort 1024 descending
  for (int k2 = 2; k2 <= 1024; k2 <<= 1) {
    for (int j = k2 >> 1; j > 0; j >>= 1) {
      int l = tid ^ j;
      if (l > tid) {
        unsigned long long a = wins[tid], bq = wins[l];
        bool sw = ((tid & k2) == 0) ? (a < bq) : (a > bq);
        if (sw) { wins[tid] = bq; wins[l] = a; }
      }
      __syncthreads();
    }
  }
  if (tid < KC) {
    unsigned long long kk = wins[tid];
    if (tid < Kt && kk != 0ULL) {
      unsigned int key32 = (unsigned int)(kk >> 32);
      unsigned int idx = 0xFFFFFFFFu - (unsigned int)(kk & 0xFFFFFFFFULL);
      int b = (int)(idx >> 18), rem = (int)(idx & (HWl - 1));
      cand_val[tid] = __uint_as_float(key32);
      cand_bid[tid] = b; cand_cy[tid] = rem >> 9; cand_cx[tid] = rem & (W_ - 1);
    } else {
      cand_val[tid] = -1e30f; cand_bid[tid] = 0; cand_cy[tid] = 0; cand_cx[tid] = 0;
    }
  }
}

// per-candidate window count of thing pixels (exact integer == f32 integral image)
__global__ __launch_bounds__(256) void k_wsum(
    const int* __restrict__ sem, const float* __restrict__ mix,
    const float* __restrict__ cand_val, const int* __restrict__ cand_bid,
    const int* __restrict__ cand_cy, const int* __restrict__ cand_cx,
    int* __restrict__ selected) {
  __shared__ int ssum[256];
  int k = blockIdx.x;
  int b = cand_bid[k], cy = cand_cy[k], cx = cand_cx[k];
  float v = cand_val[k];
  int y0 = cy - 25; if (y0 < 0) y0 = 0;
  int y1 = cy + 26; if (y1 > H_) y1 = H_;
  int x0 = cx - 25; if (x0 < 0) x0 = 0;
  int x1 = cx + 26; if (x1 > W_) x1 = W_;
  int wd = x1 - x0, tot = (y1 - y0) * wd;
  int s = 0;
  for (int t = threadIdx.x; t < tot; t += 256) {
    int yy = y0 + t / wd, xx = x0 + t % wd;
    int sv = sem[b * HWl + yy * W_ + xx];
    s += (sv >= 11 && sv <= 18) ? 1 : 0;
  }
  ssum[threadIdx.x] = s;
  __syncthreads();
  for (int o = 128; o > 0; o >>= 1) {
    if (threadIdx.x < o) ssum[threadIdx.x] += ssum[threadIdx.x + o];
    __syncthreads();
  }
  if (threadIdx.x == 0) {
    bool sel = (v >= 0.1f) && (mix[b * HWl + cy * W_ + cx] < 0.5f) && (ssum[0] >= 64);
    selected[k] = sel ? 1 : 0;
  }
}

// build per-batch packed center lists (rank order preserved), any_center, counts
__global__ __launch_bounds__(256) void k_final(
    const int* __restrict__ cand_bid, const int* __restrict__ cand_cy,
    const int* __restrict__ cand_cx, const int* __restrict__ selected,
    int* __restrict__ any_center, int* __restrict__ Sb,
    float4* __restrict__ sel_pack) {
  __shared__ int wtot0[4], wtot1[4];
  int k = threadIdx.x;
  bool sel = false; int b = 0, cy = 0, cx = 0;
  if (k < KC) { sel = selected[k] != 0; b = cand_bid[k]; cy = cand_cy[k]; cx = cand_cx[k]; }
  unsigned long long m0 = __ballot(sel && b == 0);
  unsigned long long m1 = __ballot(sel && b == 1);
  int lane = k & 63, wv = k >> 6;
  if (lane == 0) { wtot0[wv] = __popcll(m0); wtot1[wv] = __popcll(m1); }
  __syncthreads();
  int base0 = 0, base1 = 0;
  for (int w2 = 0; w2 < wv; ++w2) { base0 += wtot0[w2]; base1 += wtot1[w2]; }
  unsigned long long below = (1ULL << lane) - 1ULL;
  int p0 = base0 + __popcll(m0 & below);
  int p1 = base1 + __popcll(m1 & below);
  if (sel) {
    int lidx = (b == 0) ? p0 : p1;  // 0-based local index (ascending rank k)
    float fy = (float)cy, fx = (float)cx;
    float cc = __fadd_rn(__fmul_rn(fy, fy), __fmul_rn(fx, fx));
    sel_pack[b * 256 + lidx] = make_float4(fy, fx, cc, 0.0f);
    if (lidx == 0) any_center[b] = 1;
  }
  if (k == 0) {
    int t0 = 0, t1 = 0;
    for (int w2 = 0; w2 < 4; ++w2) { t0 += wtot0[w2]; t1 += wtot1[w2]; }
    Sb[0] = t0; Sb[1] = t1;
  }
}

// fused (4 px/thread): Gaussian max-splat + nearest-center argmin + instance ids
// + LDS-binned mass sums flushed to global per block
__global__ __launch_bounds__(256) void k_fused(
    const float* __restrict__ offs, const int* __restrict__ sem,
    const int* __restrict__ Sb, const float4* __restrict__ sel_pack,
    const int* __restrict__ any_center,
    int* __restrict__ ins, float* __restrict__ out,
    int* __restrict__ gsy, int* __restrict__ gsx, int* __restrict__ gcn) {
  __shared__ float4 sc[256];
  __shared__ int lsy[NSEG], lsx[NSEG], lcn[NSEG];
  __shared__ int Ss, s_any;
  int tid = threadIdx.x;
  int t = blockIdx.x * 256 + tid;   // t < 131072
  int p = t << 2;
  int b = p >> 18;                  // uniform per block
  if (tid == 0) { Ss = Sb[b]; s_any = any_center[b]; }
  for (int q = tid; q < NSEG; q += 256) { lsy[q] = 0; lsx[q] = 0; lcn[q] = 0; }
  __syncthreads();
  int S = Ss;
  for (int q = tid; q < S; q += 256) sc[q] = sel_pack[b * 256 + q];
  __syncthreads();
  int rem = p & (HWl - 1), y = rem >> 9, x0i = rem & (W_ - 1);
  float fy = (float)y;
  float4 oy4 = *(const float4*)(offs + b * 2 * HWl + rem);
  float4 ox4 = *(const float4*)(offs + b * 2 * HWl + HWl + rem);
  float oyv[4] = {oy4.x, oy4.y, oy4.z, oy4.w};
  float oxv[4] = {ox4.x, ox4.y, ox4.z, ox4.w};
  float lyv[4], lxv[4], llv[4], bd[4], bg[4];
  int bsg[4];
#pragma unroll
  for (int j = 0; j < 4; ++j) {
    float fx = (float)(x0i + j);
    // exact op order of reference: ll = ly*ly + lx*lx (no FMA)
    lyv[j] = __fadd_rn(fy, oyv[j]);
    lxv[j] = __fadd_rn(fx, oxv[j]);
    llv[j] = __fadd_rn(__fmul_rn(lyv[j], lyv[j]), __fmul_rn(lxv[j], lxv[j]));
    bd[j] = 3.0e38f; bg[j] = 0.0f; bsg[j] = 0;
  }
  for (int s = 0; s < S; ++s) {
    float4 c = sc[s];
#pragma unroll
    for (int j = 0; j < 4; ++j) {
      float dot = __fadd_rn(__fmul_rn(c.x, lyv[j]), __fmul_rn(c.y, lxv[j]));
      float d2 = __fadd_rn(__fsub_rn(c.z, __fmul_rn(2.0f, dot)), llv[j]);
      bool better = d2 < bd[j];  // ascending rank -> first-min tie-break (== argmin)
      bd[j] = better ? d2 : bd[j];
      bsg[j] = better ? (s + 1) : bsg[j];
    }
    float dyc = fy - c.x;
    if (fabsf(dyc) <= 25.0f) {
      float gy = expf(-__fmul_rn(__fmul_rn(dyc, dyc), INV2S2));
#pragma unroll
      for (int j = 0; j < 4; ++j) {
        float dxc = (float)(x0i + j) - c.y;
        if (fabsf(dxc) <= 25.0f) {
          float gx = expf(-__fmul_rn(__fmul_rn(dxc, dxc), INV2S2));
          bg[j] = fmaxf(bg[j], __fmul_rn(gy, gx));
        }
      }
    }
  }
  *(float4*)(out + OUT_CENTER + p) = make_float4(bg[0], bg[1], bg[2], bg[3]);
  int4 sv4 = *(const int4*)(sem + p);
  int svv[4] = {sv4.x, sv4.y, sv4.z, sv4.w};
  int insv[4];
#pragma unroll
  for (int j = 0; j < 4; ++j) {
    bool thing = (svv[j] >= 11 && svv[j] <= 18);
    insv[j] = (thing && s_any) ? bsg[j] : 0;
  }
  *(int4*)(ins + p) = make_int4(insv[0], insv[1], insv[2], insv[3]);
  // merged per-thread bin accumulation (adjacent px often share a segment)
  int curSeg = -1, aY = 0, aX = 0, aC = 0;
#pragma unroll
  for (int j = 0; j < 4; ++j) {
    if (insv[j] > 0) {
      int sg = b * (KC + 1) + insv[j];
      if (sg != curSeg) {
        if (curSeg >= 0) {
          atomicAdd(&lsy[curSeg], aY); atomicAdd(&lsx[curSeg], aX); atomicAdd(&lcn[curSeg], aC);
        }
        curSeg = sg; aY = 0; aX = 0; aC = 0;
      }
      aY += y; aX += x0i + j; aC += 1;
    }
  }
  if (curSeg >= 0) {
    atomicAdd(&lsy[curSeg], aY); atomicAdd(&lsx[curSeg], aX); atomicAdd(&lcn[curSeg], aC);
  }
  __syncthreads();
  for (int q = tid; q < NSEG; q += 256) {
    int c = lcn[q];
    if (c) { atomicAdd(&gcn[q], c); atomicAdd(&gsy[q], lsy[q]); atomicAdd(&gsx[q], lsx[q]); }
  }
}

// offsets (4 px/thread) + center/offset weights
__global__ __launch_bounds__(256) void k_off(
    const int* __restrict__ ins, const int* __restrict__ gsy,
    const int* __restrict__ gsx, const int* __restrict__ gcn,
    float* __restrict__ out) {
  int t = blockIdx.x * 256 + threadIdx.x;   // t < 131072
  int p = t << 2;
  int b = p >> 18, rem = p & (HWl - 1), y = rem >> 9, x0i = rem & (W_ - 1);
  int4 iv = *(const int4*)(ins + p);
  int insv[4] = {iv.x, iv.y, iv.z, iv.w};
  float oy[4], ox[4], ow[4];
  float fy = (float)y;
#pragma unroll
  for (int j = 0; j < 4; ++j) {
    if (insv[j] > 0) {
      int sg = b * (KC + 1) + insv[j];
      float c = fmaxf((float)gcn[sg], 1.0f);
      oy[j] = __fsub_rn((float)gsy[sg] / c, fy);
      ox[j] = __fsub_rn((float)gsx[sg] / c, (float)(x0i + j));
      ow[j] = 1.0f;
    } else { oy[j] = 0.0f; ox[j] = 0.0f; ow[j] = 0.0f; }
  }
  *(float4*)(out + OUT_OFF + b * 2 * HWl + rem) = make_float4(oy[0], oy[1], oy[2], oy[3]);
  *(float4*)(out + OUT_OFF + b * 2 * HWl + HWl + rem) = make_float4(ox[0], ox[1], ox[2], ox[3]);
  *(float4*)(out + OUT_CW + p) = make_float4(1.0f, 1.0f, 1.0f, 1.0f);
  *(float4*)(out + OUT_OW + p) = make_float4(ow[0], ow[1], ow[2], ow[3]);
}

// ---------------- launch ----------------
extern "C" void kernel_launch(void* const* d_in, const int* in_sizes, int n_in,
                              void* d_out, int out_size, void* d_ws, size_t ws_size,
                              hipStream_t stream) {
  const float* ctr = (const float*)d_in[0];
  const float* offs = (const float*)d_in[1];
  const int* sem = (const int*)d_in[2];
  const float* mix = (const float*)d_in[3];
  float* out = (float*)d_out;

  char* w = (char*)d_ws;
  int* hist16 = (int*)w;                               // 256 KB, zeroed
  int* cand_count = (int*)(w + 262144);
  int* Sb = (int*)(w + 262152);
  int* any_center = (int*)(w + 262160);
  float* cand_val = (float*)(w + 262400);
  int* cand_bid = (int*)(w + 263424);
  int* cand_cy = (int*)(w + 264448);
  int* cand_cx = (int*)(w + 265472);
  int* selected = (int*)(w + 266496);
  int* gsy = (int*)(w + 267520);
  int* gsx = (int*)(w + 269312);
  int* gcn = (int*)(w + 271104);                       // zero region ends at 272896
  float4* sel_pack = (float4*)(w + 272896);            // 8 KB
  unsigned long long* keys = (unsigned long long*)(w + 294912);  // 512 KB
  float* rowmax = (float*)(w + 1048576);               // 2 MB (dead after k_nms2)
  int* ins = (int*)(w + 1048576);                      // overlays rowmax

  k_rowmax<<<512, 256, 0, stream>>>(ctr, rowmax, (int4*)w);
  k_nms2<<<512, 256, 0, stream>>>(ctr, rowmax, keys, cand_count, hist16);
  k_topk2<<<1, 1024, 0, stream>>>(keys, cand_count, hist16,
                                  cand_val, cand_bid, cand_cy, cand_cx);
  k_wsum<<<KC, 256, 0, stream>>>(sem, mix, cand_val, cand_bid, cand_cy, cand_cx, selected);
  k_final<<<1, 256, 0, stream>>>(cand_bid, cand_cy, cand_cx, selected,
                                 any_center, Sb, sel_pack);
  k_fused<<<512, 256, 0, stream>>>(offs, sem, Sb, sel_pack, any_center,
                                   ins, out, gsy, gsx, gcn);
  k_off<<<512, 256, 0, stream>>>(ins, gsy, gsx, gcn, out);
}

// Round 5
// 80.361 us; speedup vs baseline: 3.9035x; 1.8893x over previous
//
#include <hip/hip_runtime.h>

// ---------------- problem constants ----------------
constexpr int B_ = 2, H_ = 512, W_ = 512;
constexpr int HWl = H_ * W_;          // 262144
constexpr int TOT = B_ * HWl;         // 524288
constexpr int KC = 200;               // TOP_K_INSTANCE
constexpr int CAPC = 65536;           // candidate capacity (expect ~11k peaks)
constexpr int NSEG = B_ * (KC + 1);   // 402
constexpr float INV2S2 = 0.0078125f;  // 1/128, exact power of 2

// output layout (flat float32, concatenated in return order)
constexpr int OUT_CENTER = 0;                 // [B,1,H,W]
constexpr int OUT_OFF = TOT;                  // [B,2,H,W]
constexpr int OUT_CW = TOT + 2 * TOT;         // [B,H,W] ones
constexpr int OUT_OW = OUT_CW + TOT;          // [B,H,W] fg

constexpr int ZERO_INT4 = 512;                // 8 KB zero region (counters + seg sums)

__device__ __forceinline__ float hwthr(float v) { return v > 0.1f ? v : -1.0f; }

// ---------------- kernels ----------------

// pass 1: horizontal 7-max of thresholded heatmap (4 px/thread).
// First threads also zero the ws meta region (counters + segment sums).
__global__ __launch_bounds__(256) void k_rowmax(const float* __restrict__ ctr,
                                                float* __restrict__ rowmax,
                                                int4* __restrict__ zbuf) {
  int t = blockIdx.x * 256 + threadIdx.x;     // t < 131072
  if (t < ZERO_INT4) zbuf[t] = make_int4(0, 0, 0, 0);
  int p = t << 2;
  int x4 = p & (W_ - 1);
  const float4* c4 = (const float4*)ctr;
  float4 v = c4[t];
  float4 L = make_float4(-1e30f, -1e30f, -1e30f, -1e30f), R = L;
  if (x4 >= 4) L = c4[t - 1];
  if (x4 <= W_ - 8) R = c4[t + 1];
  float a1 = hwthr(L.y), a2 = hwthr(L.z), a3 = hwthr(L.w);
  float a4 = hwthr(v.x), a5 = hwthr(v.y), a6 = hwthr(v.z), a7 = hwthr(v.w);
  float a8 = hwthr(R.x), a9 = hwthr(R.y), a10 = hwthr(R.z);
  float core = fmaxf(fmaxf(a4, a5), fmaxf(a6, a7));
  float4 m;
  m.x = fmaxf(fmaxf(a1, a2), fmaxf(a3, core));
  m.y = fmaxf(fmaxf(a2, a3), fmaxf(core, a8));
  m.z = fmaxf(fmaxf(a3, core), fmaxf(a8, a9));
  m.w = fmaxf(fmaxf(core, a8), fmaxf(a9, a10));
  ((float4*)rowmax)[t] = m;
}

// pass 2: vertical 7-max of rowmax -> pooled; peak emit.
// Peaks are staged in LDS; ONE global atomic per block reserves the key slots
// (removes the single-hot-address atomic serialization that cost 85 us).
__global__ __launch_bounds__(256) void k_nms2(const float* __restrict__ ctr,
                                              const float* __restrict__ rowmax,
                                              unsigned long long* __restrict__ keys,
                                              int* __restrict__ cand_count) {
  __shared__ unsigned long long lkeys[1024];
  __shared__ int lnum, lbase;
  int tid = threadIdx.x;
  if (tid == 0) lnum = 0;
  __syncthreads();
  int t = blockIdx.x * 256 + tid;             // t < 131072
  int p = t << 2;
  int rem = p & (HWl - 1), y = rem >> 9;
  const float4* rm4 = (const float4*)rowmax;
  float4 pool = make_float4(-1e30f, -1e30f, -1e30f, -1e30f);
#pragma unroll
  for (int dy = -3; dy <= 3; ++dy) {
    int yy = y + dy;
    if (yy < 0 || yy >= H_) continue;
    float4 r = rm4[t + dy * (W_ / 4)];
    pool.x = fmaxf(pool.x, r.x); pool.y = fmaxf(pool.y, r.y);
    pool.z = fmaxf(pool.z, r.z); pool.w = fmaxf(pool.w, r.w);
  }
  float4 v = ((const float4*)ctr)[t];
  float vv[4] = {v.x, v.y, v.z, v.w};
  float pv[4] = {pool.x, pool.y, pool.z, pool.w};
#pragma unroll
  for (int j = 0; j < 4; ++j) {
    float vj = vv[j];
    if (vj > 0.1f && vj == pv[j]) {  // exact equality, same as reference hmp==pooled
      unsigned int i = (unsigned int)(p + j);
      unsigned int key32 = __float_as_uint(vj);  // v>0 -> bits order-preserving
      unsigned long long comp = ((unsigned long long)key32 << 32)
                              | (unsigned long long)(0xFFFFFFFFu - i);
      int wslot = atomicAdd(&lnum, 1);           // LDS atomic, cheap
      lkeys[wslot] = comp;
    }
  }
  __syncthreads();
  if (tid == 0) lbase = atomicAdd(cand_count, lnum);  // one global atomic per block
  __syncthreads();
  int n = lnum, base = lbase;
  for (int q = tid; q < n; q += 256) {
    int slot = base + q;
    if (slot < CAPC) keys[slot] = lkeys[q];
  }
}

// exact top-K by (value desc, index asc), single kernel, keys L2-resident.
// 4-level radix refine of the EXACT 32-bit rank-K value: 12 bits (4096-bin LDS
// hist) then 8/8/4 bits. Collect keys with value >= V (<= K-1 + exact-value
// ties), bitonic sort 1024 desc, emit rank order.
__global__ __launch_bounds__(1024) void k_topk2(
    const unsigned long long* __restrict__ keys, const int* __restrict__ pcnt,
    float* __restrict__ cand_val, int* __restrict__ cand_bid,
    int* __restrict__ cand_cy, int* __restrict__ cand_cx) {
  __shared__ int hist[4096];
  __shared__ int sfxC[1024];
  __shared__ int hs[256];
  __shared__ int s_bin, s_r, s_num;
  __shared__ unsigned long long wins[1024];
  int tid = threadIdx.x;
  int M = *pcnt; if (M > CAPC) M = CAPC;
  int Kt = M < KC ? M : KC;

  unsigned long long thresh64 = 1ULL;  // M<=K: take everything (all keys nonzero)
  if (M > KC) {
    // ---- level 1: 4096 bins on value bits [31:20] (composite bits [63:52]) ----
    for (int q = tid; q < 4096; q += 1024) hist[q] = 0;
    __syncthreads();
    for (int idx = tid; idx < M; idx += 1024)
      atomicAdd(&hist[(int)(keys[idx] >> 52)], 1);
    __syncthreads();
    int h0 = hist[4 * tid], h1 = hist[4 * tid + 1];
    int h2 = hist[4 * tid + 2], h3 = hist[4 * tid + 3];
    sfxC[tid] = h0 + h1 + h2 + h3;
    __syncthreads();
    for (int off = 1; off < 1024; off <<= 1) {
      int v = (tid + off < 1024) ? sfxC[tid + off] : 0;
      __syncthreads();
      sfxC[tid] += v;
      __syncthreads();
    }
    if (sfxC[tid] >= Kt && (tid == 1023 || sfxC[tid + 1] < Kt)) {
      int above = (tid == 1023) ? 0 : sfxC[tid + 1];
      int s3 = above + h3, s2 = s3 + h2, s1 = s2 + h1;
      int j, sAbove;
      if (s3 >= Kt)      { j = 3; sAbove = above; }
      else if (s2 >= Kt) { j = 2; sAbove = s3; }
      else if (s1 >= Kt) { j = 1; sAbove = s2; }
      else               { j = 0; sAbove = s1; }
      s_bin = 4 * tid + j; s_r = Kt - sAbove;
    }
    __syncthreads();
    unsigned int P1 = (unsigned int)s_bin;  // value bits [31:20]
    int r1 = s_r;
    __syncthreads();

    // ---- level 2: 256 bins on value bits [19:12] ----
    if (tid < 256) hs[tid] = 0;
    __syncthreads();
    for (int idx = tid; idx < M; idx += 1024) {
      unsigned long long kk = keys[idx];
      if ((unsigned int)(kk >> 52) == P1)
        atomicAdd(&hs[(int)((kk >> 44) & 255ULL)], 1);
    }
    __syncthreads();
    for (int off = 1; off < 256; off <<= 1) {
      int v = 0;
      if (tid < 256 && tid + off < 256) v = hs[tid + off];
      __syncthreads();
      if (tid < 256) hs[tid] += v;
      __syncthreads();
    }
    if (tid < 256) {
      int above = (tid == 255) ? 0 : hs[tid + 1];
      if (hs[tid] >= r1 && above < r1) { s_bin = tid; s_r = r1 - above; }
    }
    __syncthreads();
    unsigned int P2 = (P1 << 8) | (unsigned int)s_bin;  // value bits [31:12]
    int r2 = s_r;
    __syncthreads();

    // ---- level 3: 256 bins on value bits [11:4] ----
    if (tid < 256) hs[tid] = 0;
    __syncthreads();
    for (int idx = tid; idx < M; idx += 1024) {
      unsigned long long kk = keys[idx];
      if ((unsigned int)(kk >> 44) == P2)
        atomicAdd(&hs[(int)((kk >> 36) & 255ULL)], 1);
    }
    __syncthreads();
    for (int off = 1; off < 256; off <<= 1) {
      int v = 0;
      if (tid < 256 && tid + off < 256) v = hs[tid + off];
      __syncthreads();
      if (tid < 256) hs[tid] += v;
      __syncthreads();
    }
    if (tid < 256) {
      int above = (tid == 255) ? 0 : hs[tid + 1];
      if (hs[tid] >= r2 && above < r2) { s_bin = tid; s_r = r2 - above; }
    }
    __syncthreads();
    unsigned int P3 = (P2 << 8) | (unsigned int)s_bin;  // value bits [31:4]
    int r3 = s_r;
    __syncthreads();

    // ---- level 4: 16 bins on value bits [3:0] ----
    if (tid < 16) hs[tid] = 0;
    __syncthreads();
    for (int idx = tid; idx < M; idx += 1024) {
      unsigned long long kk = keys[idx];
      if ((unsigned int)(kk >> 36) == P3)
        atomicAdd(&hs[(int)((kk >> 32) & 15ULL)], 1);
    }
    __syncthreads();
    for (int off = 1; off < 16; off <<= 1) {
      int v = 0;
      if (tid < 16 && tid + off < 16) v = hs[tid + off];
      __syncthreads();
      if (tid < 16) hs[tid] += v;
      __syncthreads();
    }
    if (tid < 16) {
      int above = (tid == 15) ? 0 : hs[tid + 1];
      if (hs[tid] >= r3 && above < r3) s_bin = tid;
    }
    __syncthreads();
    unsigned int V = (P3 << 4) | (unsigned int)s_bin;   // exact rank-K 32-bit value
    thresh64 = ((unsigned long long)V) << 32;           // value>=V <=> key>=thresh64
  }

  if (tid == 0) s_num = 0;
  __syncthreads();
  for (int idx = tid; idx < M; idx += 1024) {
    unsigned long long kk = keys[idx];
    if (kk >= thresh64) {
      int w = atomicAdd(&s_num, 1);
      if (w < 1024) wins[w] = kk;
    }
  }
  __syncthreads();
  int n = s_num; if (n > 1024) n = 1024;
  if (tid >= n) wins[tid] = 0ULL;
  __syncthreads();
  // bitonic sort 1024 descending
  for (int k2 = 2; k2 <= 1024; k2 <<= 1) {
    for (int j = k2 >> 1; j > 0; j >>= 1) {
      int l = tid ^ j;
      if (l > tid) {
        unsigned long long a = wins[tid], bq = wins[l];
        bool sw = ((tid & k2) == 0) ? (a < bq) : (a > bq);
        if (sw) { wins[tid] = bq; wins[l] = a; }
      }
      __syncthreads();
    }
  }
  if (tid < KC) {
    unsigned long long kk = wins[tid];
    if (tid < Kt && kk != 0ULL) {
      unsigned int key32 = (unsigned int)(kk >> 32);
      unsigned int idx = 0xFFFFFFFFu - (unsigned int)(kk & 0xFFFFFFFFULL);
      int b = (int)(idx >> 18), rem = (int)(idx & (HWl - 1));
      cand_val[tid] = __uint_as_float(key32);
      cand_bid[tid] = b; cand_cy[tid] = rem >> 9; cand_cx[tid] = rem & (W_ - 1);
    } else {
      cand_val[tid] = -1e30f; cand_bid[tid] = 0; cand_cy[tid] = 0; cand_cx[tid] = 0;
    }
  }
}

// per-candidate window count of thing pixels (exact integer == f32 integral image)
__global__ __launch_bounds__(256) void k_wsum(
    const int* __restrict__ sem, const float* __restrict__ mix,
    const float* __restrict__ cand_val, const int* __restrict__ cand_bid,
    const int* __restrict__ cand_cy, const int* __restrict__ cand_cx,
    int* __restrict__ selected) {
  __shared__ int ssum[256];
  int k = blockIdx.x;
  int b = cand_bid[k], cy = cand_cy[k], cx = cand_cx[k];
  float v = cand_val[k];
  int y0 = cy - 25; if (y0 < 0) y0 = 0;
  int y1 = cy + 26; if (y1 > H_) y1 = H_;
  int x0 = cx - 25; if (x0 < 0) x0 = 0;
  int x1 = cx + 26; if (x1 > W_) x1 = W_;
  int wd = x1 - x0, tot = (y1 - y0) * wd;
  int s = 0;
  for (int t = threadIdx.x; t < tot; t += 256) {
    int yy = y0 + t / wd, xx = x0 + t % wd;
    int sv = sem[b * HWl + yy * W_ + xx];
    s += (sv >= 11 && sv <= 18) ? 1 : 0;
  }
  ssum[threadIdx.x] = s;
  __syncthreads();
  for (int o = 128; o > 0; o >>= 1) {
    if (threadIdx.x < o) ssum[threadIdx.x] += ssum[threadIdx.x + o];
    __syncthreads();
  }
  if (threadIdx.x == 0) {
    bool sel = (v >= 0.1f) && (mix[b * HWl + cy * W_ + cx] < 0.5f) && (ssum[0] >= 64);
    selected[k] = sel ? 1 : 0;
  }
}

// build per-batch packed center lists (rank order preserved), any_center, counts
__global__ __launch_bounds__(256) void k_final(
    const int* __restrict__ cand_bid, const int* __restrict__ cand_cy,
    const int* __restrict__ cand_cx, const int* __restrict__ selected,
    int* __restrict__ any_center, int* __restrict__ Sb,
    float4* __restrict__ sel_pack) {
  __shared__ int wtot0[4], wtot1[4];
  int k = threadIdx.x;
  bool sel = false; int b = 0, cy = 0, cx = 0;
  if (k < KC) { sel = selected[k] != 0; b = cand_bid[k]; cy = cand_cy[k]; cx = cand_cx[k]; }
  unsigned long long m0 = __ballot(sel && b == 0);
  unsigned long long m1 = __ballot(sel && b == 1);
  int lane = k & 63, wv = k >> 6;
  if (lane == 0) { wtot0[wv] = __popcll(m0); wtot1[wv] = __popcll(m1); }
  __syncthreads();
  int base0 = 0, base1 = 0;
  for (int w2 = 0; w2 < wv; ++w2) { base0 += wtot0[w2]; base1 += wtot1[w2]; }
  unsigned long long below = (1ULL << lane) - 1ULL;
  int p0 = base0 + __popcll(m0 & below);
  int p1 = base1 + __popcll(m1 & below);
  if (sel) {
    int lidx = (b == 0) ? p0 : p1;  // 0-based local index (ascending rank k)
    float fy = (float)cy, fx = (float)cx;
    float cc = __fadd_rn(__fmul_rn(fy, fy), __fmul_rn(fx, fx));
    sel_pack[b * 256 + lidx] = make_float4(fy, fx, cc, 0.0f);
    if (lidx == 0) any_center[b] = 1;
  }
  if (k == 0) {
    int t0 = 0, t1 = 0;
    for (int w2 = 0; w2 < 4; ++w2) { t0 += wtot0[w2]; t1 += wtot1[w2]; }
    Sb[0] = t0; Sb[1] = t1;
  }
}

// fused (4 px/thread): Gaussian max-splat + nearest-center argmin + instance ids
// + LDS-binned mass sums flushed to global per block
__global__ __launch_bounds__(256) void k_fused(
    const float* __restrict__ offs, const int* __restrict__ sem,
    const int* __restrict__ Sb, const float4* __restrict__ sel_pack,
    const int* __restrict__ any_center,
    int* __restrict__ ins, float* __restrict__ out,
    int* __restrict__ gsy, int* __restrict__ gsx, int* __restrict__ gcn) {
  __shared__ float4 sc[256];
  __shared__ int lsy[NSEG], lsx[NSEG], lcn[NSEG];
  __shared__ int Ss, s_any;
  int tid = threadIdx.x;
  int t = blockIdx.x * 256 + tid;   // t < 131072
  int p = t << 2;
  int b = p >> 18;                  // uniform per block
  if (tid == 0) { Ss = Sb[b]; s_any = any_center[b]; }
  for (int q = tid; q < NSEG; q += 256) { lsy[q] = 0; lsx[q] = 0; lcn[q] = 0; }
  __syncthreads();
  int S = Ss;
  for (int q = tid; q < S; q += 256) sc[q] = sel_pack[b * 256 + q];
  __syncthreads();
  int rem = p & (HWl - 1), y = rem >> 9, x0i = rem & (W_ - 1);
  float fy = (float)y;
  float4 oy4 = *(const float4*)(offs + b * 2 * HWl + rem);
  float4 ox4 = *(const float4*)(offs + b * 2 * HWl + HWl + rem);
  float oyv[4] = {oy4.x, oy4.y, oy4.z, oy4.w};
  float oxv[4] = {ox4.x, ox4.y, ox4.z, ox4.w};
  float lyv[4], lxv[4], llv[4], bd[4], bg[4];
  int bsg[4];
#pragma unroll
  for (int j = 0; j < 4; ++j) {
    float fx = (float)(x0i + j);
    // exact op order of reference: ll = ly*ly + lx*lx (no FMA)
    lyv[j] = __fadd_rn(fy, oyv[j]);
    lxv[j] = __fadd_rn(fx, oxv[j]);
    llv[j] = __fadd_rn(__fmul_rn(lyv[j], lyv[j]), __fmul_rn(lxv[j], lxv[j]));
    bd[j] = 3.0e38f; bg[j] = 0.0f; bsg[j] = 0;
  }
  for (int s = 0; s < S; ++s) {
    float4 c = sc[s];
#pragma unroll
    for (int j = 0; j < 4; ++j) {
      float dot = __fadd_rn(__fmul_rn(c.x, lyv[j]), __fmul_rn(c.y, lxv[j]));
      float d2 = __fadd_rn(__fsub_rn(c.z, __fmul_rn(2.0f, dot)), llv[j]);
      bool better = d2 < bd[j];  // ascending rank -> first-min tie-break (== argmin)
      bd[j] = better ? d2 : bd[j];
      bsg[j] = better ? (s + 1) : bsg[j];
    }
    float dyc = fy - c.x;
    if (fabsf(dyc) <= 25.0f) {
      float gy = expf(-__fmul_rn(__fmul_rn(dyc, dyc), INV2S2));
#pragma unroll
      for (int j = 0; j < 4; ++j) {
        float dxc = (float)(x0i + j) - c.y;
        if (fabsf(dxc) <= 25.0f) {
          float gx = expf(-__fmul_rn(__fmul_rn(dxc, dxc), INV2S2));
          bg[j] = fmaxf(bg[j], __fmul_rn(gy, gx));
        }
      }
    }
  }
  *(float4*)(out + OUT_CENTER + p) = make_float4(bg[0], bg[1], bg[2], bg[3]);
  int4 sv4 = *(const int4*)(sem + p);
  int svv[4] = {sv4.x, sv4.y, sv4.z, sv4.w};
  int insv[4];
#pragma unroll
  for (int j = 0; j < 4; ++j) {
    bool thing = (svv[j] >= 11 && svv[j] <= 18);
    insv[j] = (thing && s_any) ? bsg[j] : 0;
  }
  *(int4*)(ins + p) = make_int4(insv[0], insv[1], insv[2], insv[3]);
  // merged per-thread bin accumulation (adjacent px often share a segment)
  int curSeg = -1, aY = 0, aX = 0, aC = 0;
#pragma unroll
  for (int j = 0; j < 4; ++j) {
    if (insv[j] > 0) {
      int sg = b * (KC + 1) + insv[j];
      if (sg != curSeg) {
        if (curSeg >= 0) {
          atomicAdd(&lsy[curSeg], aY); atomicAdd(&lsx[curSeg], aX); atomicAdd(&lcn[curSeg], aC);
        }
        curSeg = sg; aY = 0; aX = 0; aC = 0;
      }
      aY += y; aX += x0i + j; aC += 1;
    }
  }
  if (curSeg >= 0) {
    atomicAdd(&lsy[curSeg], aY); atomicAdd(&lsx[curSeg], aX); atomicAdd(&lcn[curSeg], aC);
  }
  __syncthreads();
  for (int q = tid; q < NSEG; q += 256) {
    int c = lcn[q];
    if (c) { atomicAdd(&gcn[q], c); atomicAdd(&gsy[q], lsy[q]); atomicAdd(&gsx[q], lsx[q]); }
  }
}

// offsets (4 px/thread) + center/offset weights
__global__ __launch_bounds__(256) void k_off(
    const int* __restrict__ ins, const int* __restrict__ gsy,
    const int* __restrict__ gsx, const int* __restrict__ gcn,
    float* __restrict__ out) {
  int t = blockIdx.x * 256 + threadIdx.x;   // t < 131072
  int p = t << 2;
  int b = p >> 18, rem = p & (HWl - 1), y = rem >> 9, x0i = rem & (W_ - 1);
  int4 iv = *(const int4*)(ins + p);
  int insv[4] = {iv.x, iv.y, iv.z, iv.w};
  float oy[4], ox[4], ow[4];
  float fy = (float)y;
#pragma unroll
  for (int j = 0; j < 4; ++j) {
    if (insv[j] > 0) {
      int sg = b * (KC + 1) + insv[j];
      float c = fmaxf((float)gcn[sg], 1.0f);
      oy[j] = __fsub_rn((float)gsy[sg] / c, fy);
      ox[j] = __fsub_rn((float)gsx[sg] / c, (float)(x0i + j));
      ow[j] = 1.0f;
    } else { oy[j] = 0.0f; ox[j] = 0.0f; ow[j] = 0.0f; }
  }
  *(float4*)(out + OUT_OFF + b * 2 * HWl + rem) = make_float4(oy[0], oy[1], oy[2], oy[3]);
  *(float4*)(out + OUT_OFF + b * 2 * HWl + HWl + rem) = make_float4(ox[0], ox[1], ox[2], ox[3]);
  *(float4*)(out + OUT_CW + p) = make_float4(1.0f, 1.0f, 1.0f, 1.0f);
  *(float4*)(out + OUT_OW + p) = make_float4(ow[0], ow[1], ow[2], ow[3]);
}

// ---------------- launch ----------------
extern "C" void kernel_launch(void* const* d_in, const int* in_sizes, int n_in,
                              void* d_out, int out_size, void* d_ws, size_t ws_size,
                              hipStream_t stream) {
  const float* ctr = (const float*)d_in[0];
  const float* offs = (const float*)d_in[1];
  const int* sem = (const int*)d_in[2];
  const float* mix = (const float*)d_in[3];
  float* out = (float*)d_out;

  char* w = (char*)d_ws;
  // zero region: [0, 8192)
  int* cand_count = (int*)(w + 0);
  int* Sb = (int*)(w + 8);
  int* any_center = (int*)(w + 16);
  int* gsy = (int*)(w + 1024);                         // 1608 B
  int* gsx = (int*)(w + 3072);
  int* gcn = (int*)(w + 5120);                         // ends 6728 < 8192
  // non-zeroed scratch
  float* cand_val = (float*)(w + 8192);
  int* cand_bid = (int*)(w + 9216);
  int* cand_cy = (int*)(w + 10240);
  int* cand_cx = (int*)(w + 11264);
  int* selected = (int*)(w + 12288);
  float4* sel_pack = (float4*)(w + 13312);             // 8 KB, ends 21504
  unsigned long long* keys = (unsigned long long*)(w + 32768);   // 512 KB
  float* rowmax = (float*)(w + 1048576);               // 2 MB (dead after k_nms2)
  int* ins = (int*)(w + 1048576);                      // overlays rowmax

  k_rowmax<<<512, 256, 0, stream>>>(ctr, rowmax, (int4*)w);
  k_nms2<<<512, 256, 0, stream>>>(ctr, rowmax, keys, cand_count);
  k_topk2<<<1, 1024, 0, stream>>>(keys, cand_count,
                                  cand_val, cand_bid, cand_cy, cand_cx);
  k_wsum<<<KC, 256, 0, stream>>>(sem, mix, cand_val, cand_bid, cand_cy, cand_cx, selected);
  k_final<<<1, 256, 0, stream>>>(cand_bid, cand_cy, cand_cx, selected,
                                 any_center, Sb, sel_pack);
  k_fused<<<512, 256, 0, stream>>>(offs, sem, Sb, sel_pack, any_center,
                                   ins, out, gsy, gsx, gcn);
  k_off<<<512, 256, 0, stream>>>(ins, gsy, gsx, gcn, out);
}